// Round 1
// baseline (410.308 us; speedup 1.0000x reference)
//
#include <hip/hip_runtime.h>
#include <hip/hip_bf16.h>

#define BATCH   64
#define LEN     288
#define DIM     256
#define PAST    12
#define NWIN    (LEN - PAST)        // 276
#define M_DIM   (BATCH * NWIN)      // 17664
#define K_DIM   (PAST * DIM)        // 3072
#define N_DIM   3072

#define BM 128
#define BN 128
#define BK 32

typedef __attribute__((ext_vector_type(8))) short bh8;     // 8 x bf16 (4 VGPRs)
typedef __attribute__((ext_vector_type(4))) float f32x4;   // MFMA accumulator

__device__ __forceinline__ void llds16(const void* g, void* l) {
    __builtin_amdgcn_global_load_lds(
        (const __attribute__((address_space(1))) unsigned int*)g,
        (__attribute__((address_space(3))) unsigned int*)l,
        16, 0, 0);
}

// f32 -> bf16 conversion, 8 floats per thread (vectorized 2x float4 in, 16B out)
__global__ void cvt_f32_bf16(const float* __restrict__ in,
                             __hip_bfloat16* __restrict__ out, int n8) {
    int i = blockIdx.x * blockDim.x + threadIdx.x;
    if (i >= n8) return;
    const float4* p = (const float4*)in;
    float4 a = p[2 * i], b = p[2 * i + 1];
    union { __hip_bfloat16 h[8]; int4 v; } u;
    u.h[0] = __float2bfloat16(a.x); u.h[1] = __float2bfloat16(a.y);
    u.h[2] = __float2bfloat16(a.z); u.h[3] = __float2bfloat16(a.w);
    u.h[4] = __float2bfloat16(b.x); u.h[5] = __float2bfloat16(b.y);
    u.h[6] = __float2bfloat16(b.z); u.h[7] = __float2bfloat16(b.w);
    ((int4*)out)[i] = u.v;
}

// row m of the windowed A matrix starts at inp + (b*LEN + w)*DIM, contiguous K_DIM elems
__device__ __forceinline__ long a_rowbase(int m) {
    int b = m / NWIN;
    int w = m - b * NWIN;
    return ((long)(b * LEN + w)) * DIM;
}

__global__ __launch_bounds__(256)
void gemm_win(const __hip_bfloat16* __restrict__ A,   // bf16 inp, BATCH*LEN*DIM
              const __hip_bfloat16* __restrict__ W,   // bf16 W, N_DIM x K_DIM row-major
              const float* __restrict__ bias,         // N_DIM
              float* __restrict__ C)                  // M_DIM x N_DIM
{
    __shared__ __hip_bfloat16 As[BM * BK];  // 8 KB, row-major [128][32]
    __shared__ __hip_bfloat16 Bs[BN * BK];  // 8 KB

    const int t   = threadIdx.x;
    const int bid = blockIdx.x;
    const int bn  = bid % (N_DIM / BN);   // fastest: consecutive blocks share A panel
    const int bm  = bid / (N_DIM / BN);
    const int tile_m = bm * BM;
    const int tile_n = bn * BN;

    // Staging: thread t covers bf16 elems [8t, 8t+8) of each 4KB half-tile.
    // Row = t/4, col = (t%4)*8 in the [*, 32] LDS tile.
    const int sr = t >> 2;
    const int sc = (t & 3) * 8;
    const long aOff0 = a_rowbase(tile_m + sr) + sc;
    const long aOff1 = a_rowbase(tile_m + 64 + sr) + sc;
    const long bOff0 = (long)(tile_n + sr) * K_DIM + sc;
    const long bOff1 = (long)(tile_n + 64 + sr) * K_DIM + sc;

    const int wave = t >> 6;
    const int lane = t & 63;
    const int wr = (wave >> 1) * 64;   // wave's sub-tile origin (64x64 per wave)
    const int wc = (wave & 1) * 64;
    const int fr = lane & 15;          // row (A) / col (B) within 16x16 fragment
    const int kg = (lane >> 4) * 8;    // k-group offset

    // global_load_lds dest: wave-uniform base + lane*16 == linear thread order
    char* asDst = (char*)As + wave * 1024;
    char* bsDst = (char*)Bs + wave * 1024;

    f32x4 acc[4][4] = {};

    for (int kt = 0; kt < K_DIM / BK; ++kt) {
        const int k0 = kt * BK;
        __syncthreads();                       // previous iter's ds_reads done
        llds16(A + aOff0 + k0, asDst);
        llds16(A + aOff1 + k0, asDst + 4096);
        llds16(W + bOff0 + k0, bsDst);
        llds16(W + bOff1 + k0, bsDst + 4096);
        __syncthreads();                       // implicit vmcnt(0) drains the loads

        bh8 af[4], bfr[4];
#pragma unroll
        for (int mi = 0; mi < 4; ++mi)
            af[mi] = *(const bh8*)(As + (wr + mi * 16 + fr) * BK + kg);
#pragma unroll
        for (int ni = 0; ni < 4; ++ni)
            bfr[ni] = *(const bh8*)(Bs + (wc + ni * 16 + fr) * BK + kg);
#pragma unroll
        for (int mi = 0; mi < 4; ++mi)
#pragma unroll
            for (int ni = 0; ni < 4; ++ni)
                acc[mi][ni] = __builtin_amdgcn_mfma_f32_16x16x32_bf16(
                    af[mi], bfr[ni], acc[mi][ni], 0, 0, 0);
    }

    // Epilogue: C/D layout col = lane&15, row = (lane>>4)*4 + j  [m89/m91]
    float bv[4];
#pragma unroll
    for (int ni = 0; ni < 4; ++ni)
        bv[ni] = bias[tile_n + wc + ni * 16 + fr];

    const int r0 = (lane >> 4) * 4;
#pragma unroll
    for (int mi = 0; mi < 4; ++mi) {
#pragma unroll
        for (int j = 0; j < 4; ++j) {
            long m = tile_m + wr + mi * 16 + r0 + j;
            float* crow = C + m * (long)N_DIM + tile_n + wc + fr;
#pragma unroll
            for (int ni = 0; ni < 4; ++ni)
                crow[ni * 16] = acc[mi][ni][j] + bv[ni];
        }
    }
}

extern "C" void kernel_launch(void* const* d_in, const int* in_sizes, int n_in,
                              void* d_out, int out_size, void* d_ws, size_t ws_size,
                              hipStream_t stream) {
    const float* inp  = (const float*)d_in[0];
    const float* Wf   = (const float*)d_in[1];
    const float* bias = (const float*)d_in[2];
    float* out = (float*)d_out;

    __hip_bfloat16* Abf = (__hip_bfloat16*)d_ws;
    __hip_bfloat16* Wbf = (__hip_bfloat16*)((char*)d_ws + (size_t)BATCH * LEN * DIM * 2);

    const int nA8 = BATCH * LEN * DIM / 8;   // 589824
    const int nW8 = N_DIM * K_DIM / 8;       // 1179648
    cvt_f32_bf16<<<(nA8 + 255) / 256, 256, 0, stream>>>(inp, Abf, nA8);
    cvt_f32_bf16<<<(nW8 + 255) / 256, 256, 0, stream>>>(Wf, Wbf, nW8);

    dim3 grid((M_DIM / BM) * (N_DIM / BN));  // 138 * 24 = 3312
    gemm_win<<<grid, 256, 0, stream>>>(Abf, Wbf, bias, out);
}

// Round 2
// 337.637 us; speedup vs baseline: 1.2152x; 1.2152x over previous
//
#include <hip/hip_runtime.h>
#include <hip/hip_bf16.h>

#define BATCH   64
#define LEN     288
#define DIM     256
#define PAST    12
#define NWIN    (LEN - PAST)        // 276
#define M_DIM   (BATCH * NWIN)      // 17664
#define K_DIM   (PAST * DIM)        // 3072
#define N_DIM   3072

#define BM 256
#define BN 256
#define BK 64
#define NTILE   (K_DIM / BK)        // 48
#define NITER   (NTILE / 2)         // 24
#define GRID_M  (M_DIM / BM)        // 69
#define GRID_N  (N_DIM / BN)        // 12

typedef __attribute__((ext_vector_type(8))) short bh8;     // 8 x bf16
typedef __attribute__((ext_vector_type(4))) float f32x4;   // MFMA accumulator

__device__ __forceinline__ void llds16(const void* g, void* l) {
    __builtin_amdgcn_global_load_lds(
        (const __attribute__((address_space(1))) unsigned int*)g,
        (__attribute__((address_space(3))) unsigned int*)l,
        16, 0, 0);
}

__global__ void cvt_f32_bf16(const float* __restrict__ in,
                             __hip_bfloat16* __restrict__ out, int n8) {
    int i = blockIdx.x * blockDim.x + threadIdx.x;
    if (i >= n8) return;
    const float4* p = (const float4*)in;
    float4 a = p[2 * i], b = p[2 * i + 1];
    union { __hip_bfloat16 h[8]; int4 v; } u;
    u.h[0] = __float2bfloat16(a.x); u.h[1] = __float2bfloat16(a.y);
    u.h[2] = __float2bfloat16(a.z); u.h[3] = __float2bfloat16(a.w);
    u.h[4] = __float2bfloat16(b.x); u.h[5] = __float2bfloat16(b.y);
    u.h[6] = __float2bfloat16(b.z); u.h[7] = __float2bfloat16(b.w);
    ((int4*)out)[i] = u.v;
}

// ---- 256x256 8-phase GEMM (T2 swizzle + T3/T4 counted vmcnt + T5 setprio) ----
// LDS: buf0 A @0 (32KB), buf0 B @32768, buf1 A @65536, buf1 B @98304. 128KB.
// Tiles [256 rows][64 cols] bf16 = 128B/row. Swizzle: 16B-chunk c at row r holds
// global chunk c^(r&7) (both write-source and read-address use the same XOR).

#define LDS_A(buf) (smem + (buf) * 65536)
#define LDS_B(buf) (smem + (buf) * 65536 + 32768)

#define PH_MID  __builtin_amdgcn_sched_barrier(0); __builtin_amdgcn_s_barrier(); \
                __builtin_amdgcn_sched_barrier(0); __builtin_amdgcn_s_setprio(1);
#define PH_END  __builtin_amdgcn_s_setprio(0); __builtin_amdgcn_sched_barrier(0); \
                __builtin_amdgcn_s_barrier(); __builtin_amdgcn_sched_barrier(0);
#define PH_END_VM __builtin_amdgcn_s_setprio(0); __builtin_amdgcn_sched_barrier(0); \
                asm volatile("s_waitcnt vmcnt(2)" ::: "memory"); \
                __builtin_amdgcn_s_barrier(); __builtin_amdgcn_sched_barrier(0);

// read 4 A m-frags (rows MB..MB+3 of this wave's half) x 2 k-steps
#define RD_A4(buf, MB) { \
    const char* _b = LDS_A(buf) + aRowB; \
    _Pragma("unroll") for (int mi = 0; mi < 4; ++mi) { \
        a0[mi][0] = *(const bh8*)(_b + (MB + mi) * 2048 + kOff0); \
        a0[mi][1] = *(const bh8*)(_b + (MB + mi) * 2048 + kOff1); \
    } }
// read 2 B n-frags x 2 k-steps into dst
#define RD_B2(buf, dst, NB) { \
    const char* _b = LDS_B(buf) + bRowB; \
    _Pragma("unroll") for (int ni = 0; ni < 2; ++ni) { \
        dst[ni][0] = *(const bh8*)(_b + (NB + ni) * 2048 + kOff0); \
        dst[ni][1] = *(const bh8*)(_b + (NB + ni) * 2048 + kOff1); \
    } }
// one C-quadrant: 4m x 2n x 2k = 16 MFMA
#define MFMA_Q(MB, NB, BB) \
    _Pragma("unroll") for (int mi = 0; mi < 4; ++mi) \
    _Pragma("unroll") for (int ni = 0; ni < 2; ++ni) { \
        acc[MB + mi][NB + ni] = __builtin_amdgcn_mfma_f32_16x16x32_bf16( \
            a0[mi][0], BB[ni][0], acc[MB + mi][NB + ni], 0, 0, 0); \
        acc[MB + mi][NB + ni] = __builtin_amdgcn_mfma_f32_16x16x32_bf16( \
            a0[mi][1], BB[ni][1], acc[MB + mi][NB + ni], 0, 0, 0); \
    }
// stage one 64-row block pair (one half-tile = 2 x global_load_lds)
#define STG_A2(buf, kt, h) { \
    llds16(Ag + aSrc[2 * (h)]     + (kt) * 64, LDS_A(buf) + (2 * (h)) * 8192 + wOff); \
    llds16(Ag + aSrc[2 * (h) + 1] + (kt) * 64, LDS_A(buf) + (2 * (h) + 1) * 8192 + wOff); }
#define STG_B2(buf, kt, h) { \
    llds16(Wg + bSrc[2 * (h)]     + (kt) * 64, LDS_B(buf) + (2 * (h)) * 8192 + wOff); \
    llds16(Wg + bSrc[2 * (h) + 1] + (kt) * 64, LDS_B(buf) + (2 * (h) + 1) * 8192 + wOff); }

__global__ __launch_bounds__(512, 2)
void gemm_win8(const __hip_bfloat16* __restrict__ Ag,   // bf16 inp
               const __hip_bfloat16* __restrict__ Wg,   // bf16 W [N][K]
               const float* __restrict__ bias,
               float* __restrict__ C)
{
    extern __shared__ char smem[];

    const int tid  = threadIdx.x;
    // bijective XCD swizzle (m204): nwg=828, 828%8=4
    const int nwg = GRID_M * GRID_N;
    const int q = nwg >> 3, r = nwg & 7;
    const int xcd = blockIdx.x & 7, loc = blockIdx.x >> 3;
    const int wgid = (xcd < r ? xcd * (q + 1) : r * (q + 1) + (xcd - r) * q) + loc;
    const int bm = wgid / GRID_N;
    const int bn = wgid - bm * GRID_N;
    const int tile_m = bm * BM;
    const int tile_n = bn * BN;

    // ---- staging addresses (per thread): row rd=tid>>3 within 64-row block,
    // source chunk = (tid&7) ^ (rd&7) (pre-swizzled global source, linear LDS dest)
    const int rd  = tid >> 3;
    const int ch  = tid & 7;
    const int chs = ((ch ^ (rd & 7)) * 8);   // source col in elements
    int aSrc[4], bSrc[4];
#pragma unroll
    for (int rb = 0; rb < 4; ++rb) {
        int m  = tile_m + rb * 64 + rd;
        int bq = m / NWIN;
        int wq = m - bq * NWIN;
        aSrc[rb] = (bq * LEN + wq) * DIM + chs;          // window row is contiguous
        bSrc[rb] = (tile_n + rb * 64 + rd) * K_DIM + chs;
    }

    // ---- fragment addressing
    const int wave = tid >> 6, lane = tid & 63;
    const int wm = wave >> 2, wn = wave & 3;             // 2M x 4N waves
    const int fr = lane & 15, kg = lane >> 4;
    const int sw    = (fr & 7) << 4;                     // read-side XOR (row&7)<<4
    const int kOff0 = (kg * 16) ^ sw;
    const int kOff1 = kOff0 ^ 64;
    const int aRowB = (wm * 128 + fr) * 128;             // byte row base in A tile
    const int bRowB = (wn * 64 + fr) * 128;              // byte row base in B tile
    const int wOff  = wave * 1024;                       // wave-uniform LDS dest

    bh8 a0[4][2], fb0[2][2], fb1[2][2];
    f32x4 acc[8][4] = {};

    // ---- prologue: tile0 -> buf0 (4 half-tiles), tile1 H0 -> buf1
    STG_A2(0, 0, 0); STG_A2(0, 0, 1); STG_B2(0, 0, 0); STG_B2(0, 0, 1);
    STG_A2(1, 1, 0);
    asm volatile("s_waitcnt vmcnt(2)" ::: "memory");     // buf0 fully landed
    __builtin_amdgcn_s_barrier();
    __builtin_amdgcn_sched_barrier(0);

#pragma unroll 1
    for (int it = 0; it < NITER; ++it) {
        const int t1 = 2 * it + 1;                        // buf1 tile (this iter)
        int t2 = 2 * it + 2; if (t2 >= NTILE) t2 = NTILE - 2;  // buf0 next (clamped)
        int t3 = 2 * it + 3; if (t3 >= NTILE) t3 = NTILE - 1;  // buf1 next (clamped)

        // ---- phases 0-3: compute buf0 (tile 2i) ----
        RD_A4(0, 0); RD_B2(0, fb0, 0);
        STG_A2(1, t1, 1);                                 // buf1 A-half1
        PH_MID; MFMA_Q(0, 0, fb0); PH_END;

        RD_B2(0, fb1, 2);
        STG_B2(1, t1, 0);                                 // buf1 B-half0
        PH_MID; MFMA_Q(0, 2, fb1); PH_END;

        RD_A4(0, 4);
        STG_B2(1, t1, 1);                                 // buf1 B-half1
        PH_MID; MFMA_Q(4, 2, fb1); PH_END;

        STG_A2(0, t2, 0);                                 // buf0 A-half0 (tile 2i+2)
        PH_MID; MFMA_Q(4, 0, fb0); PH_END_VM;             // vmcnt(2): buf1 landed

        // ---- phases 4-7: compute buf1 (tile 2i+1) ----
        RD_A4(1, 0); RD_B2(1, fb0, 0);
        STG_A2(0, t2, 1);                                 // buf0 A-half1
        PH_MID; MFMA_Q(0, 0, fb0); PH_END;

        RD_B2(1, fb1, 2);
        STG_B2(0, t2, 0);                                 // buf0 B-half0
        PH_MID; MFMA_Q(0, 2, fb1); PH_END;

        RD_A4(1, 4);
        STG_B2(0, t2, 1);                                 // buf0 B-half1
        PH_MID; MFMA_Q(4, 2, fb1); PH_END;

        STG_A2(1, t3, 0);                                 // buf1 A-half0 (tile 2i+3)
        PH_MID; MFMA_Q(4, 0, fb0); PH_END_VM;             // vmcnt(2): buf0 landed
    }

    // ---- epilogue: C = acc + bias; C/D layout col=lane&15, row=(lane>>4)*4+j
    float bv[4];
    const float* bp = bias + tile_n + wn * 64 + fr;
#pragma unroll
    for (int ni = 0; ni < 4; ++ni) bv[ni] = bp[ni * 16];

    const int r0 = (lane >> 4) * 4;
#pragma unroll
    for (int mi = 0; mi < 8; ++mi) {
#pragma unroll
        for (int j = 0; j < 4; ++j) {
            long m = tile_m + wm * 128 + mi * 16 + r0 + j;
            float* crow = C + m * (long)N_DIM + tile_n + wn * 64 + fr;
#pragma unroll
            for (int ni = 0; ni < 4; ++ni)
                crow[ni * 16] = acc[mi][ni][j] + bv[ni];
        }
    }
}

extern "C" void kernel_launch(void* const* d_in, const int* in_sizes, int n_in,
                              void* d_out, int out_size, void* d_ws, size_t ws_size,
                              hipStream_t stream) {
    const float* inp  = (const float*)d_in[0];
    const float* Wf   = (const float*)d_in[1];
    const float* bias = (const float*)d_in[2];
    float* out = (float*)d_out;

    __hip_bfloat16* Abf = (__hip_bfloat16*)d_ws;
    __hip_bfloat16* Wbf = (__hip_bfloat16*)((char*)d_ws + (size_t)BATCH * LEN * DIM * 2);

    const int nA8 = BATCH * LEN * DIM / 8;
    const int nW8 = N_DIM * K_DIM / 8;
    cvt_f32_bf16<<<(nA8 + 255) / 256, 256, 0, stream>>>(inp, Abf, nA8);
    cvt_f32_bf16<<<(nW8 + 255) / 256, 256, 0, stream>>>(Wf, Wbf, nW8);

    hipFuncSetAttribute((const void*)gemm_win8,
                        hipFuncAttributeMaxDynamicSharedMemorySize, 131072);
    gemm_win8<<<dim3(GRID_M * GRID_N), 512, 131072, stream>>>(Abf, Wbf, bias, out);
}